// Round 11
// baseline (1391.487 us; speedup 1.0000x reference)
//
#include <hip/hip_runtime.h>

// 5-layer GRU, H=20, B=256, T=4096, fp32. PyTorch GRU math.
// One block per batch element; 5 waves = one per layer. Pre-scaled weights
// (-log2e on r/z rows, -2log2e on n rows) so sigmoid/tanh need no leading
// multiply. Pairwise flag sync on depth-4 ring (no per-chunk __syncthreads).
//
// R15 (863 us): DS-broadcast refresh (1 ds_write + 5 uniform ds_read_b128)
// replaced 20 v_readlane; h lands in VGPR quads so FMA chains pack.
// R17: IN-LANE TRIPLE MATVEC — remove both ds_bpermutes from the serial
// chain. Counter evidence: per-step budget 505 cyc vs ~120-160 issue cyc,
// VALUBusy 41% == (1 shared SIMD ~64% + 3 solo ~32%)/4 -> pace is per-wave
// CHAIN LATENCY; the chain held TWO LDS round trips (~120 cyc each, m117):
// refresh and the zf bpermute. Now the unit lane computes ALL THREE gate
// rows itself (15 f4-FMAs, 3 independent 5-deep chains): ghr/ghz/ghn are
// local, sigmoid-z and tanh-n need no cross-lane transport. Ring reads are
// 3 positions (u, u+20, u+40; 20 consecutive addrs each, conflict-free,
// prefetched). z-row/n-row math replicates lanes i+20/i+40's current
// computation bit-for-bit (same weights/pairing/horizontal/binit). Lanes
// >=20 duplicate unit 19 (junk, unread); proj stays 60-lane-wide.

#define HH 20
#define GG 60
#define NL 5
#define BB 256
#define TT 4096
#define KK 16
#define NC (TT / KK)
#define RD 4            // ring depth (chunks of drift allowed)

typedef float f4 __attribute__((ext_vector_type(4)));

struct Params {
  const float* x;
  const float* wih[NL];
  const float* whh[NL];
  const float* bih[NL];
  const float* bhh[NL];
  const float* wout;
  const float* bout;
  float* out;
};

__device__ __forceinline__ float bcast_dyn(float v, int j) {    // j: sgpr/imm
  return __int_as_float(__builtin_amdgcn_readlane(__float_as_int(v), j));
}
// input pre-scaled by -log2e: sigmoid(x) = rcp(1 + exp2(x_scaled))
__device__ __forceinline__ float fsig_s(float xs) {
  return __builtin_amdgcn_rcpf(1.0f + __builtin_amdgcn_exp2f(xs));
}
// input pre-scaled by -2log2e: tanh(y) = 2*rcp(1 + exp2(y_scaled)) - 1
__device__ __forceinline__ float ftanh_s(float ys) {
  return fmaf(2.0f, __builtin_amdgcn_rcpf(1.0f + __builtin_amdgcn_exp2f(ys)), -1.0f);
}
__device__ __forceinline__ int ldv(const int* p) {
  return *(const volatile int*)p;
}

__global__ __launch_bounds__(NL * 64, 1) void gru5_kernel(Params p) {
  // ring: producer layer l (0..3) writes xring[l][c%RD]; consumer l+1 reads.
  // KK+1 rows so the consumer's t+1 prefetch is unguarded (row KK = junk).
  __shared__ float xring[NL - 1][RD][KK + 1][64];
  // per-wave h broadcast buffer (write 20 lanes, read back wave-uniform)
  __shared__ __align__(16) float hbuf[NL][32];
  __shared__ float yp[NL];
  __shared__ int prog[NL - 1];   // chunks produced by layer l
  __shared__ int cons[NL - 1];   // chunks consumed by layer l+1

  const int tid = threadIdx.x;
  const int l = tid >> 6;          // wave index == layer
  const int lane = tid & 63;
  const int b = blockIdx.x;
  const int g = lane < GG ? lane : GG - 1;   // proj row owned by this lane
  const int u = lane < HH ? lane : HH - 1;   // unit owned (lanes >=20 dup 19)

  if (tid < NL - 1) { prog[tid] = 0; cons[tid] = 0; }

  const float S1 = -1.44269504088896f;   // -log2(e)      (r/z rows)
  const float S2 = -2.88539008177793f;   // -2*log2(e)    (n rows)
  const float scg = (g < 2 * HH) ? S1 : S2;

  // ---- W_hh rows for unit u: r (u), z (u+20), n (u+40) — f4 quads ----
  f4 wr4[5], wz4[5], wn4[5];
  {
    const float* W = p.whh[l];
    const float* Wr = W + (size_t)u * HH;
    const float* Wz = W + (size_t)(u + HH) * HH;
    const float* Wn = W + (size_t)(u + 2 * HH) * HH;
    #pragma unroll
    for (int k = 0; k < 5; ++k) {
      wr4[k].x = Wr[4 * k] * S1;  wr4[k].y = Wr[4 * k + 1] * S1;
      wr4[k].z = Wr[4 * k + 2] * S1;  wr4[k].w = Wr[4 * k + 3] * S1;
      wz4[k].x = Wz[4 * k] * S1;  wz4[k].y = Wz[4 * k + 1] * S1;
      wz4[k].z = Wz[4 * k + 2] * S1;  wz4[k].w = Wz[4 * k + 3] * S1;
      wn4[k].x = Wn[4 * k] * S2;  wn4[k].y = Wn[4 * k + 1] * S2;
      wn4[k].z = Wn[4 * k + 2] * S2;  wn4[k].w = Wn[4 * k + 3] * S2;
    }
  }
  const float bnn = p.bhh[l][u + 2 * HH] * S2;   // b_hh_n seed (n-row matvec)

  // next-layer proj weights (row g of W_ih[l+1]) — unchanged, 60 lanes
  f4 wnx4[5];
  float bnx = 0.0f;
  if (l < NL - 1) {
    const float* W = p.wih[l + 1];
    #pragma unroll
    for (int k = 0; k < 5; ++k) {
      wnx4[k].x = W[g * HH + 4 * k]     * scg;
      wnx4[k].y = W[g * HH + 4 * k + 1] * scg;
      wnx4[k].z = W[g * HH + 4 * k + 2] * scg;
      wnx4[k].w = W[g * HH + 4 * k + 3] * scg;
    }
    bnx = (p.bih[l + 1][g] + (g < 2 * HH ? p.bhh[l + 1][g] : 0.0f)) * scg;
  } else {
    #pragma unroll
    for (int k = 0; k < 5; ++k) { wnx4[k].x = 0.f; wnx4[k].y = 0.f; wnx4[k].z = 0.f; wnx4[k].w = 0.f; }
  }
  // L0: per-unit x weights for rows u, u+20, u+40 of W_ih[0] (in_sz = 1)
  float w0r = 0.f, b0r = 0.f, w0z = 0.f, b0z = 0.f, w0n = 0.f, b0n = 0.f;
  if (l == 0) {
    w0r = p.wih[0][u] * S1;
    b0r = (p.bih[0][u] + p.bhh[0][u]) * S1;
    w0z = p.wih[0][u + HH] * S1;
    b0z = (p.bih[0][u + HH] + p.bhh[0][u + HH]) * S1;
    w0n = p.wih[0][u + 2 * HH] * S2;
    b0n = p.bih[0][u + 2 * HH] * S2;     // b_ih only (b_hh_n lives in bnn)
  }

  float hreg = 0.0f;               // lanes 0..19 carry h[unit]
  f4 hq[5];                        // all-lane copy of h (via LDS broadcast)
  #pragma unroll
  for (int k = 0; k < 5; ++k) { hq[k].x = 0.f; hq[k].y = 0.f; hq[k].z = 0.f; hq[k].w = 0.f; }

  const float* xrow = p.x + (size_t)b * TT;
  float* hout = p.out + (size_t)b * TT * HH;

  // triple hh matvec in the unit lane: ghr/ghz (S1-scaled), ghn (S2-scaled,
  // seeded with b_hh_n) — three independent 5-deep f4 chains (ILP). Each
  // replicates the old per-lane matvec bit-for-bit (same pairing/reduce).
  float ghr, ghz, ghn;
  auto matvec3 = [&]() {
    f4 ar; ar.x = 0.f;  ar.y = 0.f; ar.z = 0.f; ar.w = 0.f;
    f4 az; az.x = 0.f;  az.y = 0.f; az.z = 0.f; az.w = 0.f;
    f4 an; an.x = bnn;  an.y = 0.f; an.z = 0.f; an.w = 0.f;
    #pragma unroll
    for (int k = 0; k < 5; ++k) {
      ar = __builtin_elementwise_fma(wr4[k], hq[k], ar);
      az = __builtin_elementwise_fma(wz4[k], hq[k], az);
      an = __builtin_elementwise_fma(wn4[k], hq[k], an);
    }
    ghr = (ar.x + ar.z) + (ar.y + ar.w);
    ghz = (az.x + az.z) + (az.y + az.w);
    ghn = (an.x + an.z) + (an.y + an.w);
  };
  // LDS-broadcast of h: 1 conflict-free ds_write (lanes 0-19) + 5 uniform
  // ds_read_b128. Compiler-only fence orders write<reads; HW executes a
  // wave's DS ops in order. Bits identical to readlane transport.
  auto refresh_hs = [&]() {
    if (lane < HH) hbuf[l][lane] = hreg;
    asm volatile("" ::: "memory");           // compile-time ordering only
    const f4* hv = (const f4*)&hbuf[l][0];
    hq[0] = hv[0]; hq[1] = hv[1]; hq[2] = hv[2]; hq[3] = hv[3]; hq[4] = hv[4];
  };
  auto proj = [&]() -> float {     // next layer's xg value for this lane
    f4 c; c.x = bnx; c.y = 0.f; c.z = 0.f; c.w = 0.f;
    #pragma unroll
    for (int k = 0; k < 5; ++k) c = __builtin_elementwise_fma(wnx4[k], hq[k], c);
    return (c.x + c.z) + (c.y + c.w);
  };
  // one GRU step, fully in-lane: xr/xz/xn are the x-side preacts for rows
  // u / u+20 / u+40 (biases included, scaled). No cross-lane on the chain.
  auto gru_step = [&](float xr, float xz, float xn) {
    matvec3();
    const float svr = xr + ghr;
    const float svz = xz + ghz;
    const float sgr = fsig_s(svr);            // r for this unit
    const float sgz = fsig_s(svz);            // z for this unit (in-lane!)
    const float n = ftanh_s(fmaf(sgr, ghn, xn));
    hreg = fmaf(sgz, hreg - n, n);            // (1-z)*n + z*h
  };

  __syncthreads();                 // flags initialized

  // prime layer-0 x stage for chunk 0 (lanes 0..KK-1 hold the chunk's x)
  float xstage = 0.0f;
  if (l == 0 && lane < KK) xstage = xrow[lane];

  for (int c = 0; c < NC; ++c) {
    // --- sync: wait for input chunk; backpressure on ring slot reuse ---
    if (l > 0) {
      while (ldv(&prog[l - 1]) < c + 1) __builtin_amdgcn_s_sleep(1);
    }
    if (l < NL - 1) {
      while (ldv(&cons[l]) < c + 1 - RD) __builtin_amdgcn_s_sleep(1);
    }

    if (l == 0) {
      float* dst = &xring[0][c & (RD - 1)][0][0];
      // prefetch next chunk's x (a whole chunk of latency to hide)
      float xnl = 0.0f;
      if (lane < KK && c + 1 < NC) xnl = xrow[(c + 1) * KK + lane];
      for (int t = 0; t < KK; ++t) {
        const float xv = bcast_dyn(xstage, t);
        if (t > 0) dst[(t - 1) * 64 + lane] = proj();   // shadow: row t-1 (h(t-1))
        gru_step(fmaf(w0r, xv, b0r), fmaf(w0z, xv, b0z), fmaf(w0n, xv, b0n));
        refresh_hs();
      }
      dst[(KK - 1) * 64 + lane] = proj();         // flush last row before flag
      xstage = xnl;
    } else if (l < NL - 1) {
      const float* src = &xring[l - 1][c & (RD - 1)][0][0];
      float* dst = &xring[l][c & (RD - 1)][0][0];
      float xr_c = src[u];
      float xz_c = src[u + HH];
      float xn_c = src[u + 2 * HH];
      for (int t = 0; t < KK; ++t) {
        const float* nsrc = src + (t + 1) * 64;   // row KK exists (junk, dead)
        const float xr_n = nsrc[u];
        const float xz_n = nsrc[u + HH];
        const float xn_n = nsrc[u + 2 * HH];
        if (t > 0) dst[(t - 1) * 64 + lane] = proj();
        gru_step(xr_c, xz_c, xn_c);
        refresh_hs();
        xr_c = xr_n; xz_c = xz_n; xn_c = xn_n;
      }
      dst[(KK - 1) * 64 + lane] = proj();
    } else {
      const float* src = &xring[NL - 2][c & (RD - 1)][0][0];
      float* hp = hout + (size_t)c * KK * HH;
      float xr_c = src[u];
      float xz_c = src[u + HH];
      float xn_c = src[u + 2 * HH];
      for (int t = 0; t < KK; ++t) {
        const float* nsrc = src + (t + 1) * 64;
        const float xr_n = nsrc[u];
        const float xz_n = nsrc[u + HH];
        const float xn_n = nsrc[u + 2 * HH];
        if (t > 0 && lane < HH) hp[(t - 1) * HH + lane] = hreg;  // h(t-1)
        gru_step(xr_c, xz_c, xn_c);
        refresh_hs();                       // keeps hq fresh for next iter
        xr_c = xr_n; xz_c = xz_n; xn_c = xn_n;
      }
      if (lane < HH) hp[(KK - 1) * HH + lane] = hreg;
    }

    // --- publish: producer flags chunk done; consumer frees ring slot ---
    if (l < NL - 1) {
      __threadfence_block();               // drain LDS writes before flag
      if (lane == 0) *(volatile int*)&prog[l] = c + 1;
    }
    if (l > 0) {
      if (lane == 0) *(volatile int*)&cons[l - 1] = c + 1;
    }
  }

  // ---- epilogue: h_n + y_hat partial (per wave, then one final barrier) ----
  if (lane < HH)
    p.out[(size_t)BB * TT * HH + (size_t)b * NL * HH + l * HH + lane] = hreg;
  float pp = (lane < HH) ? hreg * p.wout[l * HH + lane] : 0.0f;
  #pragma unroll
  for (int off = 32; off > 0; off >>= 1) pp += __shfl_down(pp, off);
  if (lane == 0) yp[l] = pp;

  __syncthreads();
  if (tid == 0) {
    float y = p.bout[0];
    #pragma unroll
    for (int ll = 0; ll < NL; ++ll) y += yp[ll];
    p.out[(size_t)BB * TT * HH + (size_t)BB * NL * HH + b] = y;
  }
}

extern "C" void kernel_launch(void* const* d_in, const int* in_sizes, int n_in,
                              void* d_out, int out_size, void* d_ws, size_t ws_size,
                              hipStream_t stream) {
  Params p;
  p.x = (const float*)d_in[0];
  for (int l = 0; l < NL; ++l) {
    p.wih[l] = (const float*)d_in[1 + 4 * l];
    p.whh[l] = (const float*)d_in[2 + 4 * l];
    p.bih[l] = (const float*)d_in[3 + 4 * l];
    p.bhh[l] = (const float*)d_in[4 + 4 * l];
  }
  p.wout = (const float*)d_in[1 + 4 * NL];
  p.bout = (const float*)d_in[2 + 4 * NL];
  p.out = (float*)d_out;

  gru5_kernel<<<BB, NL * 64, 0, stream>>>(p);
}